// Round 1
// baseline (73.617 us; speedup 1.0000x reference)
//
#include <hip/hip_runtime.h>

#define NCH 64
#define IMG 256
#define KSEL 8
#define CAP 64           // max candidates per row (mean ~13, max over 512 rows ~28)
#define NG 4             // channel groups (blockIdx.z)
#define CG (NCH / NG)    // 16 channels per block
#define FSTR 5           // float4 per candidate row (4 data + 1 pad; 80 B, 16B-aligned)

__global__ __launch_bounds__(256, 4) void raster_blend_kernel(
    const float* __restrict__ pts3D,  // [B, P, 3]
    const float* __restrict__ src,    // [B, C, P]
    float* __restrict__ out,          // [B, C, H, W]
    int P)
{
    const int h = blockIdx.x;
    const int b = blockIdx.y;
    const int g = blockIdx.z;
    const int w = threadIdx.x;
    const int HW = IMG * IMG;

    const float r_ndc  = (1.5f / (float)IMG) * 2.0f;
    const float r2     = r_ndc * r_ndc;
    const float inv_r2 = 1.0f / r2;

    const float yf = 1.0f - (2.0f * (float)h + 1.0f) / (float)IMG;
    const float xf = 1.0f - (2.0f * (float)w + 1.0f) / (float)IMG;

    __shared__ __align__(16) float4 cand[CAP];            // {px, py, pz, idx-bits}
    __shared__ int cnt;
    __shared__ __align__(16) float4 featS[CAP * FSTR];    // 5120 B (16 ch / candidate)
    if (w == 0) cnt = 0;
    __syncthreads();

    // ---- Phase 1: row-filter all points into packed LDS candidate list ----
    // (duplicated across the NG channel-group blocks; pts3D is 24 KB, L1/L2-hot)
    const float* pb = pts3D + (size_t)b * P * 3;
    for (int p = w; p < P; p += 256) {
        float px = -pb[p * 3 + 0];
        float py = -pb[p * 3 + 1];
        float pz =  pb[p * 3 + 2];
        float dy = yf - py;
        if (dy * dy <= r2 && pz > 0.0f) {
            int slot = atomicAdd(&cnt, 1);
            if (slot < CAP)
                cand[slot] = make_float4(px, py, pz, __int_as_float(p));
        }
    }
    __syncthreads();
    const int n = min(cnt, CAP);

    // ---- Phase 1b-i: issue this group's feature gather into REGISTERS ----
    // thread (jr, cc): jr = w>>4 walks candidates, cc = w&15 is the channel
    // within this block's 16-channel group. L2 latency hides under selection.
    const int jr = w >> 4;    // 0..15
    const int cc = w & 15;    // 0..15
    const float* sb = src + ((size_t)b * NCH + (size_t)(g * CG + cc)) * P;
    int   cidx[CAP / 16];
    float freg[CAP / 16];
#pragma unroll
    for (int r = 0; r < CAP / 16; ++r) {
        int j = r * 16 + jr;
        if (j < n) cidx[r] = __float_as_int(cand[j].w);   // LDS broadcast reads
    }
#pragma unroll
    for (int r = 0; r < CAP / 16; ++r) {
        int j = r * 16 + jr;
        if (j < n) freg[r] = sb[cidx[r]];                 // independent L2 gathers
    }

    // ---- Phase 2: K-nearest-in-z selection (b128 broadcast per candidate) ----
    const float SENT = 1e30f;
    float zb[KSEL], db[KSEL];
    int   jb[KSEL];
#pragma unroll
    for (int s = 0; s < KSEL; ++s) { zb[s] = SENT; db[s] = 0.0f; jb[s] = 0; }

    for (int j = 0; j < n; ++j) {
        float4 e = cand[j];
        float dx = xf - e.x;
        float dy = yf - e.y;
        float d2 = fmaf(dx, dx, dy * dy);
        float z  = e.z;
        if (d2 <= r2 && z < zb[KSEL - 1]) {
            float carz = z, card = d2;
            int   carj = j;
#pragma unroll
            for (int s = 0; s < KSEL; ++s) {
                if (carz < zb[s]) {
                    float tz = zb[s]; zb[s] = carz; carz = tz;
                    float td = db[s]; db[s] = card; card = td;
                    int   tj = jb[s]; jb[s] = carj; carj = tj;
                }
            }
        }
    }

    // ---- alpha-composite weights (front-to-back) ----
    float wk[KSEL];
    float T = 1.0f;
#pragma unroll
    for (int s = 0; s < KSEL; ++s) {
        bool valid = zb[s] < 1e29f;
        float dn = db[s] * inv_r2;
        dn = fminf(fmaxf(dn, 0.001f), 1.0f);
        float a = 1.0f - sqrtf(dn);
        a = valid ? a : 0.0f;
        wk[s] = a * T;
        T *= (1.0f - a);
    }

    // ---- Phase 1b-ii: commit staged features to LDS (loads now complete) ----
    float* fS = (float*)featS;
#pragma unroll
    for (int r = 0; r < CAP / 16; ++r) {
        int j = r * 16 + jr;
        if (j < n) fS[j * (FSTR * 4) + cc] = freg[r];
    }
    __syncthreads();

    // ---- channel accumulation from LDS feature cache (16 channels) ----
    float4 acc[CG / 4];
#pragma unroll
    for (int c4 = 0; c4 < CG / 4; ++c4) acc[c4] = make_float4(0.f, 0.f, 0.f, 0.f);

    const float4* fv = featS;
#pragma unroll
    for (int k = 0; k < KSEL; ++k) {
        // slots are z-sorted with invalids (SENT) at the tail: once no lane in
        // the wave has a valid slot k, none has a valid slot >k either.
        if (!__any(zb[k] < 1e29f)) break;
        float wv = wk[k];                      // 0 for invalid lanes
        const float4* fp = fv + (size_t)jb[k] * FSTR;   // jb=0 safe (row 0 written when n>0)
#pragma unroll
        for (int c4 = 0; c4 < CG / 4; ++c4) {
            float4 f = fp[c4];
            acc[c4].x = fmaf(wv, f.x, acc[c4].x);
            acc[c4].y = fmaf(wv, f.y, acc[c4].y);
            acc[c4].z = fmaf(wv, f.z, acc[c4].z);
            acc[c4].w = fmaf(wv, f.w, acc[c4].w);
        }
    }

    // ---- coalesced stores (256 B per wave-instruction, 16 channels) ----
    float* op = out + ((size_t)b * NCH + (size_t)(g * CG)) * HW + (size_t)h * IMG + w;
#pragma unroll
    for (int c4 = 0; c4 < CG / 4; ++c4) {
        op[(size_t)(4 * c4 + 0) * HW] = acc[c4].x;
        op[(size_t)(4 * c4 + 1) * HW] = acc[c4].y;
        op[(size_t)(4 * c4 + 2) * HW] = acc[c4].z;
        op[(size_t)(4 * c4 + 3) * HW] = acc[c4].w;
    }
}

extern "C" void kernel_launch(void* const* d_in, const int* in_sizes, int n_in,
                              void* d_out, int out_size, void* d_ws, size_t ws_size,
                              hipStream_t stream) {
    const float* pts3D = (const float*)d_in[0];
    const float* src   = (const float*)d_in[1];
    float* out = (float*)d_out;

    const int B = out_size / (NCH * IMG * IMG);
    const int P = in_sizes[0] / (3 * B);

    dim3 grid(IMG, B, NG);
    dim3 block(256, 1, 1);
    raster_blend_kernel<<<grid, block, 0, stream>>>(pts3D, src, out, P);
}